// Round 2
// baseline (1284.724 us; speedup 1.0000x reference)
//
#include <hip/hip_runtime.h>
#include <hip/hip_bf16.h>
#include <stdint.h>

typedef __bf16 bf16;
typedef __bf16 bf16x8 __attribute__((ext_vector_type(8)));
typedef __bf16 bf16x4 __attribute__((ext_vector_type(4)));
typedef float  f32x4  __attribute__((ext_vector_type(4)));

#define LDS_PTR(p) ((__attribute__((address_space(3))) uint32_t*)(p))
#define GLB_PTR(p) ((const __attribute__((address_space(1))) uint32_t*)(p))

static constexpr int BATCH = 4, SEQ = 4096, DMODEL = 1024;
static constexpr int DI = 2048;
static constexpr int MTOK = BATCH * SEQ;   // 16384 tokens

// ---------------------------------------------------------------------------
// Generic bf16 MFMA GEMM:  C[m,n] = sum_k Act[m,k] * W[n,k]  (+ epilogue)
// 128x128 tile, 256 threads = 4 waves (2x2), each wave 4x4 16x16x32 MFMAs.
// m97 structure: global_load_lds width=16, 2-barrier K-loop.
// ---------------------------------------------------------------------------
enum { EPI_SPLIT = 0, EPI_PLAIN = 1, EPI_GATE = 2, EPI_RES = 3 };

template <int EPI>
__global__ __launch_bounds__(256) void gemm_bt(
    const bf16* __restrict__ Aact, const bf16* __restrict__ W,
    const float* __restrict__ bias,
    bf16* __restrict__ out0, bf16* __restrict__ out1,
    const bf16* __restrict__ gate,
    float* __restrict__ outf, const float* __restrict__ resid,
    int N, int K, int ldC, int col_off)
{
  __shared__ __align__(16) bf16 sA[128 * 32];
  __shared__ __align__(16) bf16 sB[128 * 32];
  const int tid  = threadIdx.x;
  const int n0   = blockIdx.x * 128;
  const int m0   = blockIdx.y * 128;
  const int lane = tid & 63;
  const int wv   = tid >> 6;
  const int wr   = wv >> 1, wc = wv & 1;
  const int l15  = lane & 15, quad = lane >> 4;

  f32x4 acc[4][4];
#pragma unroll
  for (int i = 0; i < 4; ++i)
#pragma unroll
    for (int j = 0; j < 4; ++j) acc[i][j] = (f32x4){0.f, 0.f, 0.f, 0.f};

  // staging: 512 chunks of 16B per 8KB tile; thread handles chunks tid, tid+256
  const int c0 = tid, c1 = tid + 256;
  const int r0 = c0 >> 2, r1 = c1 >> 2;                // tile row 0..127
  const int cb0 = (c0 & 3) * 16, cb1 = (c1 & 3) * 16;  // byte offset in 64B row

  const char* gA = (const char*)(Aact + (size_t)m0 * K);
  const char* gW = (const char*)(W + (size_t)n0 * K);

  for (int k0 = 0; k0 < K; k0 += 32) {
    if (k0) __syncthreads();
    __builtin_amdgcn_global_load_lds(GLB_PTR(gA + ((size_t)r0 * K + k0) * 2 + cb0),
                                     LDS_PTR(sA + c0 * 8), 16, 0, 0);
    __builtin_amdgcn_global_load_lds(GLB_PTR(gA + ((size_t)r1 * K + k0) * 2 + cb1),
                                     LDS_PTR(sA + c1 * 8), 16, 0, 0);
    __builtin_amdgcn_global_load_lds(GLB_PTR(gW + ((size_t)r0 * K + k0) * 2 + cb0),
                                     LDS_PTR(sB + c0 * 8), 16, 0, 0);
    __builtin_amdgcn_global_load_lds(GLB_PTR(gW + ((size_t)r1 * K + k0) * 2 + cb1),
                                     LDS_PTR(sB + c1 * 8), 16, 0, 0);
    __syncthreads();

    bf16x8 av[4], bv[4];
#pragma unroll
    for (int t = 0; t < 4; ++t) {
      av[t] = *(const bf16x8*)(sA + (wr * 64 + t * 16 + l15) * 32 + quad * 8);
      bv[t] = *(const bf16x8*)(sB + (wc * 64 + t * 16 + l15) * 32 + quad * 8);
    }
#pragma unroll
    for (int i = 0; i < 4; ++i)
#pragma unroll
      for (int j = 0; j < 4; ++j)
        acc[i][j] = __builtin_amdgcn_mfma_f32_16x16x32_bf16(av[i], bv[j], acc[i][j], 0, 0, 0);
  }

  // epilogue: C/D layout col = lane&15, row = quad*4 + r (m89-verified)
#pragma unroll
  for (int i = 0; i < 4; ++i) {
    const int mbase = m0 + wr * 64 + i * 16 + quad * 4;
#pragma unroll
    for (int j = 0; j < 4; ++j) {
      const int n = n0 + wc * 64 + j * 16 + l15;
      const float bj = bias[n];
#pragma unroll
      for (int r = 0; r < 4; ++r) {
        const int mm = mbase + r;
        float v = acc[i][j][r] + bj;
        if (EPI == EPI_SPLIT) {
          if (n < DI) out0[(size_t)mm * DI + n] = (bf16)(1.f / (1.f + __expf(-v)));
          else        out1[(size_t)mm * DI + (n - DI)] = (bf16)v;
        } else if (EPI == EPI_PLAIN) {
          out0[(size_t)mm * ldC + col_off + n] = (bf16)v;
        } else if (EPI == EPI_GATE) {
          float g = (float)gate[(size_t)mm * DI + n];
          out0[(size_t)mm * ldC + n] = (bf16)(v * g);
        } else {  // EPI_RES: fp32 out + residual
          outf[(size_t)mm * ldC + n] = v + resid[(size_t)mm * ldC + n];
        }
      }
    }
  }
}

// ---------------------------------------------------------------------------
// RMSNorm: one block per token row (1024 fp32 -> 1024 bf16)
// ---------------------------------------------------------------------------
__global__ __launch_bounds__(256) void rmsnorm_kernel(
    const float* __restrict__ x, const float* __restrict__ w, bf16* __restrict__ out)
{
  const int row = blockIdx.x;
  const int tid = threadIdx.x;
  const float4 xv = ((const float4*)(x + (size_t)row * DMODEL))[tid];
  float s = xv.x * xv.x + xv.y * xv.y + xv.z * xv.z + xv.w * xv.w;
#pragma unroll
  for (int o = 32; o; o >>= 1) s += __shfl_xor(s, o);
  __shared__ float red[4];
  if ((tid & 63) == 0) red[tid >> 6] = s;
  __syncthreads();
  const float tot = red[0] + red[1] + red[2] + red[3];
  const float scale = rsqrtf(tot * (1.f / DMODEL) + 1e-6f);
  const float4 wv = ((const float4*)w)[tid];
  bf16x4 o4 = { (bf16)(xv.x * wv.x * scale), (bf16)(xv.y * wv.y * scale),
                (bf16)(xv.z * wv.z * scale), (bf16)(xv.w * wv.w * scale) };
  *(bf16x4*)(out + (size_t)row * DMODEL + tid * 4) = o4;
}

// ---------------------------------------------------------------------------
// 9-tap depthwise conv + silu:  bsilu = silu(dwconv9(val) + sym_b)
// win[j] = val[l + j - 4].  grid: (SEQ/TL, DI/256, BATCH), thread = channel.
// ---------------------------------------------------------------------------
static constexpr int TL = 128;
__global__ __launch_bounds__(256) void conv_kernel(
    const bf16* __restrict__ val,
    const float* __restrict__ sym_k, const float* __restrict__ sym_b,
    bf16* __restrict__ bbuf)
{
  const int d  = blockIdx.y * 256 + threadIdx.x;
  const int b  = blockIdx.z;
  const int l0 = blockIdx.x * TL;
  float wk9[9];
#pragma unroll
  for (int k = 0; k < 9; ++k) wk9[k] = sym_k[d * 9 + k];
  const float bs = sym_b[d];
  const bf16* base = val + (size_t)b * SEQ * DI + d;

  float win[9];
#pragma unroll
  for (int j = 0; j < 8; ++j) {
    int xr = l0 + j - 4;
    win[j] = (xr >= 0 && xr < SEQ) ? (float)base[(size_t)xr * DI] : 0.f;
  }
  for (int t = 0; t < TL; ++t) {
    int xf = l0 + t + 4;
    win[8] = (xf < SEQ) ? (float)base[(size_t)xf * DI] : 0.f;
    float sb = bs;
#pragma unroll
    for (int k = 0; k < 9; ++k) sb += win[k] * wk9[k];
    bbuf[((size_t)b * SEQ + l0 + t) * DI + d] = (bf16)(sb / (1.f + __expf(-sb)));
#pragma unroll
    for (int k = 0; k < 8; ++k) win[k] = win[k + 1];
  }
}

// ---------------------------------------------------------------------------
// s16 partials: s16p[wave][tok][s] = sum over this wave's 512 channels of
//   (dwa_b[d] + sum_k val[l-1+k, d]*dwa_k[d,k]) * A[d,s]
// grid: (SEQ/8, BATCH), 256 threads (thread = 8 channels), A in 64KB LDS.
// ---------------------------------------------------------------------------
__global__ __launch_bounds__(256) void s16_kernel(
    const bf16* __restrict__ val,
    const float* __restrict__ dwa_k, const float* __restrict__ dwa_b,
    const float* __restrict__ A, float* __restrict__ s16p)
{
  __shared__ __align__(16) bf16 As[16 * 2048];   // As[s*2048 + d], 64 KB
  const int tid = threadIdx.x;
  // load A (2048x16 fp32) transposed into LDS as bf16
  for (int d = tid; d < 2048; d += 256) {
    const float4* ar = (const float4*)(A + d * 16);
    float4 a0 = ar[0], a1 = ar[1], a2 = ar[2], a3 = ar[3];
    As[0 * 2048 + d] = (bf16)a0.x;  As[1 * 2048 + d] = (bf16)a0.y;
    As[2 * 2048 + d] = (bf16)a0.z;  As[3 * 2048 + d] = (bf16)a0.w;
    As[4 * 2048 + d] = (bf16)a1.x;  As[5 * 2048 + d] = (bf16)a1.y;
    As[6 * 2048 + d] = (bf16)a1.z;  As[7 * 2048 + d] = (bf16)a1.w;
    As[8 * 2048 + d] = (bf16)a2.x;  As[9 * 2048 + d] = (bf16)a2.y;
    As[10 * 2048 + d] = (bf16)a2.z; As[11 * 2048 + d] = (bf16)a2.w;
    As[12 * 2048 + d] = (bf16)a3.x; As[13 * 2048 + d] = (bf16)a3.y;
    As[14 * 2048 + d] = (bf16)a3.z; As[15 * 2048 + d] = (bf16)a3.w;
  }
  const int d0 = tid * 8;
  float kk[4][8], bb[8];
#pragma unroll
  for (int j = 0; j < 8; ++j) bb[j] = dwa_b[d0 + j];
#pragma unroll
  for (int j = 0; j < 8; ++j)
#pragma unroll
    for (int k = 0; k < 4; ++k) kk[k][j] = dwa_k[(d0 + j) * 4 + k];
  __syncthreads();

  const int b = blockIdx.y, l0 = blockIdx.x * 8;
  const int lane = tid & 63, wv = tid >> 6;
  const bf16* vb = val + (size_t)b * SEQ * DI + d0;

  for (int t = 0; t < 8; ++t) {
    const int l = l0 + t;
    float a[8];
#pragma unroll
    for (int j = 0; j < 8; ++j) a[j] = bb[j];
#pragma unroll
    for (int k = 0; k < 4; ++k) {
      const int r = l - 1 + k;
      if ((unsigned)r < (unsigned)SEQ) {
        bf16x8 v = *(const bf16x8*)(vb + (size_t)r * DI);
#pragma unroll
        for (int j = 0; j < 8; ++j) a[j] += (float)v[j] * kk[k][j];
      }
    }
    float prod[16];
#pragma unroll
    for (int s = 0; s < 16; ++s) {
      bf16x8 r8 = *(const bf16x8*)(As + s * 2048 + d0);
      float p = 0.f;
#pragma unroll
      for (int j = 0; j < 8; ++j) p += a[j] * (float)r8[j];
      prod[s] = p;
    }
    const size_t obase = ((size_t)wv * MTOK + (size_t)b * SEQ + l) * 16;
#pragma unroll
    for (int s = 0; s < 16; ++s) {
      float v = prod[s];
#pragma unroll
      for (int off = 32; off; off >>= 1) v += __shfl_xor(v, off);
      if (lane == s) s16p[obase + s] = v;
    }
  }
}

// ---------------------------------------------------------------------------
// T1[s,o] = sum_d Bm[s,d] * ha_w[o,d]   (16 x 1024). One block per o.
// ---------------------------------------------------------------------------
__global__ __launch_bounds__(256) void t1_kernel(
    const float* __restrict__ Bm, const float* __restrict__ ha_w, float* __restrict__ T1)
{
  const int o = blockIdx.x, tid = threadIdx.x;
  float acc[16];
#pragma unroll
  for (int s = 0; s < 16; ++s) acc[s] = 0.f;
  for (int d = tid; d < 2048; d += 256) {
    const float w = ha_w[(size_t)o * 2048 + d];
#pragma unroll
    for (int s = 0; s < 16; ++s) acc[s] += Bm[s * 2048 + d] * w;
  }
  const int lane = tid & 63, wv = tid >> 6;
  __shared__ float red[4][16];
#pragma unroll
  for (int s = 0; s < 16; ++s) {
    float v = acc[s];
#pragma unroll
    for (int off = 32; off; off >>= 1) v += __shfl_xor(v, off);
    if (lane == s) red[wv][s] = v;
  }
  __syncthreads();
  if (tid < 16)
    T1[tid * 1024 + o] = red[0][tid] + red[1][tid] + red[2][tid] + red[3][tid];
}

// ---------------------------------------------------------------------------
// y_a = (sum_w s16p[w]) @ T1 + ha_b  ->  y[:, :1024] bf16 (ldC = 2048)
// grid: MTOK/32 blocks; T1 (64KB) in LDS; thread = 4 output cols.
// ---------------------------------------------------------------------------
__global__ __launch_bounds__(256) void ya_kernel(
    const float* __restrict__ s16p, const float* __restrict__ T1,
    const float* __restrict__ ha_b, bf16* __restrict__ y)
{
  __shared__ __align__(16) float sT[16 * 1024];
  const int tid = threadIdx.x;
  for (int i = tid; i < 4096; i += 256) ((float4*)sT)[i] = ((const float4*)T1)[i];
  const float4 bias = ((const float4*)ha_b)[tid];
  __syncthreads();
  const int tok0 = blockIdx.x * 32;
  for (int t = 0; t < 32; ++t) {
    const int tok = tok0 + t;
    float4 sv4[4];
#pragma unroll
    for (int i = 0; i < 4; ++i) sv4[i] = ((const float4*)(s16p + (size_t)tok * 16))[i];
#pragma unroll
    for (int w = 1; w < 4; ++w)
#pragma unroll
      for (int i = 0; i < 4; ++i) {
        float4 v = ((const float4*)(s16p + ((size_t)w * MTOK + tok) * 16))[i];
        sv4[i].x += v.x; sv4[i].y += v.y; sv4[i].z += v.z; sv4[i].w += v.w;
      }
    float sv[16] = { sv4[0].x, sv4[0].y, sv4[0].z, sv4[0].w,
                     sv4[1].x, sv4[1].y, sv4[1].z, sv4[1].w,
                     sv4[2].x, sv4[2].y, sv4[2].z, sv4[2].w,
                     sv4[3].x, sv4[3].y, sv4[3].z, sv4[3].w };
    float4 o = bias;
#pragma unroll
    for (int s = 0; s < 16; ++s) {
      const float4 tr = ((const float4*)(sT + s * 1024))[tid];
      o.x += sv[s] * tr.x; o.y += sv[s] * tr.y;
      o.z += sv[s] * tr.z; o.w += sv[s] * tr.w;
    }
    bf16x4 ob = { (bf16)o.x, (bf16)o.y, (bf16)o.z, (bf16)o.w };
    *(bf16x4*)(y + (size_t)tok * 2048 + tid * 4) = ob;
  }
}

// ---------------------------------------------------------------------------
// fp32 -> bf16 weight conversion
// ---------------------------------------------------------------------------
__global__ __launch_bounds__(256) void cvt_kernel(
    const float* __restrict__ in, bf16* __restrict__ out)
{
  const size_t i = (size_t)blockIdx.x * 256 + threadIdx.x;
  const float4 v = ((const float4*)in)[i];
  bf16x4 o4 = { (bf16)v.x, (bf16)v.y, (bf16)v.z, (bf16)v.w };
  *(bf16x4*)(out + 4 * i) = o4;
}

// ---------------------------------------------------------------------------
extern "C" void kernel_launch(void* const* d_in, const int* in_sizes, int n_in,
                              void* d_out, int out_size, void* d_ws, size_t ws_size,
                              hipStream_t stream)
{
  const float* x      = (const float*)d_in[0];
  const float* norm_w = (const float*)d_in[1];
  const float* in_w   = (const float*)d_in[2];
  const float* in_b   = (const float*)d_in[3];
  const float* dwa_k  = (const float*)d_in[4];
  const float* dwa_b  = (const float*)d_in[5];
  const float* Amat   = (const float*)d_in[6];
  const float* Bm     = (const float*)d_in[7];
  const float* sym_k  = (const float*)d_in[8];
  const float* sym_b  = (const float*)d_in[9];
  const float* pw_w   = (const float*)d_in[10];
  const float* pw_b   = (const float*)d_in[11];
  const float* ha_w   = (const float*)d_in[12];
  const float* ha_b   = (const float*)d_in[13];
  const float* hb_w   = (const float*)d_in[14];
  const float* hb_b   = (const float*)d_in[15];
  const float* fuse_w = (const float*)d_in[16];
  const float* fuse_b = (const float*)d_in[17];
  const float* out_w  = (const float*)d_in[18];
  const float* out_b  = (const float*)d_in[19];
  float* out = (float*)d_out;

  char* ws = (char*)d_ws;
  const size_t MB = 1u << 20;
  // Overlay plan (221 MB total):
  //  R0 [0,64):   in_wbf[0,8) + hnorm[8,40)  ->  bsilu  ->  y (concat)
  //  R1 [64,128): val  ->  pwout  ->  y2
  //  R2 [128,192): gate
  //  [192,221): bf16 weights + T1 + s16 partials
  bf16*  in_wbf  = (bf16*)(ws + 0);
  bf16*  hnorm   = (bf16*)(ws + 8 * MB);
  bf16*  bsilu   = (bf16*)(ws + 0);
  bf16*  ybuf    = (bf16*)(ws + 0);
  bf16*  valp    = (bf16*)(ws + 64 * MB);
  bf16*  pwout   = (bf16*)(ws + 64 * MB);
  bf16*  y2buf   = (bf16*)(ws + 64 * MB);
  bf16*  gatep   = (bf16*)(ws + 128 * MB);
  bf16*  pw_bf   = (bf16*)(ws + 192 * MB);   // 8 MB
  bf16*  fuse_bf = (bf16*)(ws + 200 * MB);   // 8 MB
  bf16*  hb_bf   = (bf16*)(ws + 208 * MB);   // 4 MB
  bf16*  out_bf  = (bf16*)(ws + 212 * MB);   // 4 MB
  float* T1      = (float*)(ws + 216 * MB);  // 64 KB
  float* s16p    = (float*)(ws + 217 * MB);  // 4 MB (4 wave-partials)

  // weight prep (runs every call; d_ws is re-poisoned before each launch)
  cvt_kernel<<<4096, 256, 0, stream>>>(in_w, in_wbf);
  cvt_kernel<<<4096, 256, 0, stream>>>(pw_w, pw_bf);
  cvt_kernel<<<4096, 256, 0, stream>>>(fuse_w, fuse_bf);
  cvt_kernel<<<2048, 256, 0, stream>>>(hb_w, hb_bf);
  cvt_kernel<<<2048, 256, 0, stream>>>(out_w, out_bf);
  t1_kernel<<<1024, 256, 0, stream>>>(Bm, ha_w, T1);

  // 1) rmsnorm
  rmsnorm_kernel<<<MTOK, 256, 0, stream>>>(x, norm_w, hnorm);
  // 2) in-proj GEMM: gate = sigmoid(h[:, :DI]), val = h[:, DI:]
  gemm_bt<EPI_SPLIT><<<dim3(32, 128), 256, 0, stream>>>(
      hnorm, in_wbf, in_b, gatep, valp, nullptr, nullptr, nullptr, 4096, 1024, DI, 0);
  // 3) 9-tap conv + silu  (val -> bsilu, overlays dead in_wbf/hnorm)
  conv_kernel<<<dim3(SEQ / TL, DI / 256, BATCH), 256, 0, stream>>>(
      valp, sym_k, sym_b, bsilu);
  // 4) a-branch low-rank: s16 partials (val -> s16p)
  s16_kernel<<<dim3(SEQ / 8, BATCH), 256, 0, stream>>>(valp, dwa_k, dwa_b, Amat, s16p);
  // 5) pw GEMM on silu branch (bsilu -> pwout; pwout overlays dead val)
  gemm_bt<EPI_PLAIN><<<dim3(16, 128), 256, 0, stream>>>(
      bsilu, pw_bf, pw_b, pwout, nullptr, nullptr, nullptr, nullptr, 2048, 2048, 2048, 0);
  // 6) y[:, :1024] = s16 @ T1 + ha_b   (y overlays dead bsilu)
  ya_kernel<<<MTOK / 32, 256, 0, stream>>>(s16p, T1, ha_b, ybuf);
  // 7) y[:, 1024:] = hb GEMM (pwout)
  gemm_bt<EPI_PLAIN><<<dim3(8, 128), 256, 0, stream>>>(
      pwout, hb_bf, hb_b, ybuf, nullptr, nullptr, nullptr, nullptr, 1024, 2048, 2048, 1024);
  // 8) fuse GEMM with gate multiply -> y2 (overlays dead pwout)
  gemm_bt<EPI_GATE><<<dim3(16, 128), 256, 0, stream>>>(
      ybuf, fuse_bf, fuse_b, y2buf, nullptr, gatep, nullptr, nullptr, 2048, 2048, 2048, 0);
  // 9) out GEMM + residual -> fp32 d_out
  gemm_bt<EPI_RES><<<dim3(8, 128), 256, 0, stream>>>(
      y2buf, out_bf, out_b, nullptr, nullptr, nullptr, out, x, 1024, 2048, 1024, 0);
}

// Round 3
// 1074.075 us; speedup vs baseline: 1.1961x; 1.1961x over previous
//
#include <hip/hip_runtime.h>
#include <hip/hip_bf16.h>
#include <stdint.h>

typedef __bf16 bf16;
typedef __bf16 bf16x8 __attribute__((ext_vector_type(8)));
typedef __bf16 bf16x4 __attribute__((ext_vector_type(4)));
typedef float  f32x4  __attribute__((ext_vector_type(4)));

#define LDS_PTR(p) ((__attribute__((address_space(3))) uint32_t*)(p))
#define GLB_PTR(p) ((const __attribute__((address_space(1))) uint32_t*)(p))

static constexpr int BATCH = 4, SEQ = 4096, DMODEL = 1024;
static constexpr int DI = 2048;
static constexpr int MTOK = BATCH * SEQ;   // 16384 tokens

// ---------------------------------------------------------------------------
// Generic bf16 MFMA GEMM:  C[m,n] = sum_k Act[m,k] * W[n,k]  (+ epilogue)
// 128x128 tile, 4 waves, 4x4 16x16x32 MFMAs/wave (m97 structure).
// GM=8 group swizzle: with round-robin block->XCD dispatch, each XCD sweeps
// n-tiles at a fixed m-row -> A-row pins in that XCD's L2, W streams via L3.
// ---------------------------------------------------------------------------
enum { EPI_SPLIT = 0, EPI_PLAIN = 1, EPI_GATE = 2, EPI_RES = 3 };

template <int EPI>
__global__ __launch_bounds__(256) void gemm_bt(
    const bf16* __restrict__ Aact, const bf16* __restrict__ W,
    const float* __restrict__ bias,
    bf16* __restrict__ out0, bf16* __restrict__ out1,
    const bf16* __restrict__ gate,
    float* __restrict__ outf, const float* __restrict__ resid,
    int N, int K, int ldC, int col_off)
{
  __shared__ __align__(16) bf16 sA[128 * 32];
  __shared__ __align__(16) bf16 sB[128 * 32];
  const int tid  = threadIdx.x;
  // GM=8 swizzle (gridDim.y is always a multiple of 8 here)
  const int nT   = gridDim.x;
  const int lin  = blockIdx.y * nT + blockIdx.x;
  const int grp  = lin / (8 * nT);
  const int within = lin - grp * (8 * nT);
  const int n0   = (within >> 3) * 128;
  const int m0   = (grp * 8 + (within & 7)) * 128;
  const int lane = tid & 63;
  const int wv   = tid >> 6;
  const int wr   = wv >> 1, wc = wv & 1;
  const int l15  = lane & 15, quad = lane >> 4;

  f32x4 acc[4][4];
#pragma unroll
  for (int i = 0; i < 4; ++i)
#pragma unroll
    for (int j = 0; j < 4; ++j) acc[i][j] = (f32x4){0.f, 0.f, 0.f, 0.f};

  // staging: 512 chunks of 16B per 8KB tile; thread handles chunks tid, tid+256
  const int c0 = tid, c1 = tid + 256;
  const int r0 = c0 >> 2, r1 = c1 >> 2;                // tile row 0..127
  const int cb0 = (c0 & 3) * 16, cb1 = (c1 & 3) * 16;  // byte offset in 64B row

  const char* gA = (const char*)(Aact + (size_t)m0 * K);
  const char* gW = (const char*)(W + (size_t)n0 * K);

  for (int k0 = 0; k0 < K; k0 += 32) {
    if (k0) __syncthreads();
    __builtin_amdgcn_global_load_lds(GLB_PTR(gA + ((size_t)r0 * K + k0) * 2 + cb0),
                                     LDS_PTR(sA + c0 * 8), 16, 0, 0);
    __builtin_amdgcn_global_load_lds(GLB_PTR(gA + ((size_t)r1 * K + k0) * 2 + cb1),
                                     LDS_PTR(sA + c1 * 8), 16, 0, 0);
    __builtin_amdgcn_global_load_lds(GLB_PTR(gW + ((size_t)r0 * K + k0) * 2 + cb0),
                                     LDS_PTR(sB + c0 * 8), 16, 0, 0);
    __builtin_amdgcn_global_load_lds(GLB_PTR(gW + ((size_t)r1 * K + k0) * 2 + cb1),
                                     LDS_PTR(sB + c1 * 8), 16, 0, 0);
    __syncthreads();

    bf16x8 av[4], bv[4];
#pragma unroll
    for (int t = 0; t < 4; ++t) {
      av[t] = *(const bf16x8*)(sA + (wr * 64 + t * 16 + l15) * 32 + quad * 8);
      bv[t] = *(const bf16x8*)(sB + (wc * 64 + t * 16 + l15) * 32 + quad * 8);
    }
#pragma unroll
    for (int i = 0; i < 4; ++i)
#pragma unroll
      for (int j = 0; j < 4; ++j)
        acc[i][j] = __builtin_amdgcn_mfma_f32_16x16x32_bf16(av[i], bv[j], acc[i][j], 0, 0, 0);
  }

  // epilogue: C/D layout col = lane&15, row = quad*4 + r (m89-verified)
#pragma unroll
  for (int i = 0; i < 4; ++i) {
    const int mbase = m0 + wr * 64 + i * 16 + quad * 4;
#pragma unroll
    for (int j = 0; j < 4; ++j) {
      const int n = n0 + wc * 64 + j * 16 + l15;
      const float bj = bias ? bias[n] : 0.f;
#pragma unroll
      for (int r = 0; r < 4; ++r) {
        const int mm = mbase + r;
        float v = acc[i][j][r] + bj;
        if (EPI == EPI_SPLIT) {
          if (n < DI) out0[(size_t)mm * DI + n] = (bf16)(1.f / (1.f + __expf(-v)));
          else        out1[(size_t)mm * DI + (n - DI)] = (bf16)v;
        } else if (EPI == EPI_PLAIN) {
          out0[(size_t)mm * ldC + col_off + n] = (bf16)v;
        } else if (EPI == EPI_GATE) {
          float g = (float)gate[(size_t)mm * DI + n];
          out0[(size_t)mm * ldC + n] = (bf16)(v * g);
        } else {  // EPI_RES: fp32 out + residual
          outf[(size_t)mm * ldC + n] = v + resid[(size_t)mm * ldC + n];
        }
      }
    }
  }
}

// ---------------------------------------------------------------------------
// RMSNorm: one block per token row (1024 fp32 -> 1024 bf16)
// ---------------------------------------------------------------------------
__global__ __launch_bounds__(256) void rmsnorm_kernel(
    const float* __restrict__ x, const float* __restrict__ w, bf16* __restrict__ out)
{
  const int row = blockIdx.x;
  const int tid = threadIdx.x;
  const float4 xv = ((const float4*)(x + (size_t)row * DMODEL))[tid];
  float s = xv.x * xv.x + xv.y * xv.y + xv.z * xv.z + xv.w * xv.w;
#pragma unroll
  for (int o = 32; o; o >>= 1) s += __shfl_xor(s, o);
  __shared__ float red[4];
  if ((tid & 63) == 0) red[tid >> 6] = s;
  __syncthreads();
  const float tot = red[0] + red[1] + red[2] + red[3];
  const float scale = rsqrtf(tot * (1.f / DMODEL) + 1e-6f);
  const float4 wv = ((const float4*)w)[tid];
  bf16x4 o4 = { (bf16)(xv.x * wv.x * scale), (bf16)(xv.y * wv.y * scale),
                (bf16)(xv.z * wv.z * scale), (bf16)(xv.w * wv.w * scale) };
  *(bf16x4*)(out + (size_t)row * DMODEL + tid * 4) = o4;
}

// ---------------------------------------------------------------------------
// 9-tap depthwise conv + silu, 4 channels/thread (bf16x4 loads).
// win row r = l + j - 4. grid: (SEQ/TL2, DI/1024, BATCH).
// ---------------------------------------------------------------------------
static constexpr int TL2 = 64;
__global__ __launch_bounds__(256) void conv_kernel(
    const bf16* __restrict__ val,
    const float* __restrict__ sym_k, const float* __restrict__ sym_b,
    bf16* __restrict__ bbuf)
{
  const int d  = (blockIdx.y * 256 + threadIdx.x) * 4;
  const int b  = blockIdx.z;
  const int l0 = blockIdx.x * TL2;
  float wk[9][4], bs[4];
#pragma unroll
  for (int j = 0; j < 4; ++j) {
    bs[j] = sym_b[d + j];
#pragma unroll
    for (int k = 0; k < 9; ++k) wk[k][j] = sym_k[(d + j) * 9 + k];
  }
  const bf16* base = val + (size_t)b * SEQ * DI + d;

  float win[9][4];
#pragma unroll
  for (int j = 0; j < 8; ++j) {
    const int xr = l0 + j - 4;
    if (xr >= 0 && xr < SEQ) {
      bf16x4 v = *(const bf16x4*)(base + (size_t)xr * DI);
#pragma unroll
      for (int c = 0; c < 4; ++c) win[j][c] = (float)v[c];
    } else {
#pragma unroll
      for (int c = 0; c < 4; ++c) win[j][c] = 0.f;
    }
  }
  for (int t = 0; t < TL2; ++t) {
    const int xf = l0 + t + 4;
    if (xf < SEQ) {
      bf16x4 v = *(const bf16x4*)(base + (size_t)xf * DI);
#pragma unroll
      for (int c = 0; c < 4; ++c) win[8][c] = (float)v[c];
    } else {
#pragma unroll
      for (int c = 0; c < 4; ++c) win[8][c] = 0.f;
    }
    float sb[4];
#pragma unroll
    for (int c = 0; c < 4; ++c) sb[c] = bs[c];
#pragma unroll
    for (int k = 0; k < 9; ++k)
#pragma unroll
      for (int c = 0; c < 4; ++c) sb[c] += win[k][c] * wk[k][c];
    bf16x4 o;
#pragma unroll
    for (int c = 0; c < 4; ++c) o[c] = (bf16)(sb[c] / (1.f + __expf(-sb[c])));
    *(bf16x4*)(bbuf + ((size_t)b * SEQ + l0 + t) * DI + d) = o;
#pragma unroll
    for (int k = 0; k < 8; ++k)
#pragma unroll
      for (int c = 0; c < 4; ++c) win[k][c] = win[k + 1][c];
  }
}

// ---------------------------------------------------------------------------
// Wp[n][d] = dwa_k[d,k] * A[d,s] for n = k*16+s (n<64); 0 for n in [64,128).
// (folded conv4+A weight for the skinny P GEMM; padded to N=128)
// ---------------------------------------------------------------------------
__global__ __launch_bounds__(256) void wprep_kernel(
    const float* __restrict__ dwa_k, const float* __restrict__ A, bf16* __restrict__ Wp)
{
  const int d = blockIdx.x * 256 + threadIdx.x;  // 0..2047
  float kk[4], av[16];
#pragma unroll
  for (int k = 0; k < 4; ++k) kk[k] = dwa_k[d * 4 + k];
#pragma unroll
  for (int s = 0; s < 16; ++s) av[s] = A[d * 16 + s];
#pragma unroll
  for (int k = 0; k < 4; ++k)
#pragma unroll
    for (int s = 0; s < 16; ++s)
      Wp[(size_t)(k * 16 + s) * 2048 + d] = (bf16)(kk[k] * av[s]);
  for (int n = 64; n < 128; ++n) Wp[(size_t)n * 2048 + d] = (bf16)0.f;
}

// cvec[s] = sum_d dwa_b[d] * A[d,s]   (conv bias folded through A)
__global__ __launch_bounds__(256) void cvec_kernel(
    const float* __restrict__ dwa_b, const float* __restrict__ A, float* __restrict__ cvec)
{
  const int tid = threadIdx.x;
  float acc[16];
#pragma unroll
  for (int s = 0; s < 16; ++s) acc[s] = 0.f;
  for (int d = tid; d < 2048; d += 256) {
    const float w = dwa_b[d];
#pragma unroll
    for (int s = 0; s < 16; ++s) acc[s] += w * A[d * 16 + s];
  }
  const int lane = tid & 63, wv = tid >> 6;
  __shared__ float red[4][16];
#pragma unroll
  for (int s = 0; s < 16; ++s) {
    float v = acc[s];
#pragma unroll
    for (int off = 32; off; off >>= 1) v += __shfl_xor(v, off);
    if (lane == s) red[wv][s] = v;
  }
  __syncthreads();
  if (tid < 16) cvec[tid] = red[0][tid] + red[1][tid] + red[2][tid] + red[3][tid];
}

// ---------------------------------------------------------------------------
// T1[s,o] = sum_d Bm[s,d] * ha_w[o,d]   (16 x 1024). One block per o.
// ---------------------------------------------------------------------------
__global__ __launch_bounds__(256) void t1_kernel(
    const float* __restrict__ Bm, const float* __restrict__ ha_w, float* __restrict__ T1)
{
  const int o = blockIdx.x, tid = threadIdx.x;
  float acc[16];
#pragma unroll
  for (int s = 0; s < 16; ++s) acc[s] = 0.f;
  for (int d = tid; d < 2048; d += 256) {
    const float w = ha_w[(size_t)o * 2048 + d];
#pragma unroll
    for (int s = 0; s < 16; ++s) acc[s] += Bm[s * 2048 + d] * w;
  }
  const int lane = tid & 63, wv = tid >> 6;
  __shared__ float red[4][16];
#pragma unroll
  for (int s = 0; s < 16; ++s) {
    float v = acc[s];
#pragma unroll
    for (int off = 32; off; off >>= 1) v += __shfl_xor(v, off);
    if (lane == s) red[wv][s] = v;
  }
  __syncthreads();
  if (tid < 16)
    T1[tid * 1024 + o] = red[0][tid] + red[1][tid] + red[2][tid] + red[3][tid];
}

// ---------------------------------------------------------------------------
// y_a: s16[l,s] = cvec[s] + sum_k P[l-1+k, 16k+s]  (in-batch rows only), then
// y[:, :1024] = s16 @ T1 + ha_b.  One block = 32 tokens; T1 in 64KB LDS.
// ---------------------------------------------------------------------------
__global__ __launch_bounds__(256) void ya_kernel(
    const bf16* __restrict__ P, const float* __restrict__ T1,
    const float* __restrict__ cvec, const float* __restrict__ ha_b,
    bf16* __restrict__ y)
{
  __shared__ __align__(16) float sT[16 * 1024];
  __shared__ float s16t[32][16];
  const int tid = threadIdx.x;
  for (int i = tid; i < 4096; i += 256) ((float4*)sT)[i] = ((const float4*)T1)[i];
  const int tok0 = blockIdx.x * 32;
  for (int p = tid; p < 512; p += 256) {
    const int t = p >> 4, s = p & 15;
    const int tok = tok0 + t;
    const int l = tok & (SEQ - 1), bb = tok >> 12;
    float acc = cvec[s];
#pragma unroll
    for (int k = 0; k < 4; ++k) {
      const int r = l - 1 + k;
      if ((unsigned)r < (unsigned)SEQ)
        acc += (float)P[((size_t)bb * SEQ + r) * 128 + k * 16 + s];
    }
    s16t[t][s] = acc;
  }
  const float4 bias = ((const float4*)ha_b)[tid];
  __syncthreads();
  for (int t = 0; t < 32; ++t) {
    float sv[16];
#pragma unroll
    for (int s = 0; s < 16; ++s) sv[s] = s16t[t][s];
    float4 o = bias;
#pragma unroll
    for (int s = 0; s < 16; ++s) {
      const float4 tr = ((const float4*)(sT + s * 1024))[tid];
      o.x += sv[s] * tr.x; o.y += sv[s] * tr.y;
      o.z += sv[s] * tr.z; o.w += sv[s] * tr.w;
    }
    bf16x4 ob = { (bf16)o.x, (bf16)o.y, (bf16)o.z, (bf16)o.w };
    *(bf16x4*)(y + (size_t)(tok0 + t) * 2048 + tid * 4) = ob;
  }
}

// ---------------------------------------------------------------------------
// fp32 -> bf16 weight conversion
// ---------------------------------------------------------------------------
__global__ __launch_bounds__(256) void cvt_kernel(
    const float* __restrict__ in, bf16* __restrict__ out)
{
  const size_t i = (size_t)blockIdx.x * 256 + threadIdx.x;
  const float4 v = ((const float4*)in)[i];
  bf16x4 o4 = { (bf16)v.x, (bf16)v.y, (bf16)v.z, (bf16)v.w };
  *(bf16x4*)(out + 4 * i) = o4;
}

// ---------------------------------------------------------------------------
extern "C" void kernel_launch(void* const* d_in, const int* in_sizes, int n_in,
                              void* d_out, int out_size, void* d_ws, size_t ws_size,
                              hipStream_t stream)
{
  const float* x      = (const float*)d_in[0];
  const float* norm_w = (const float*)d_in[1];
  const float* in_w   = (const float*)d_in[2];
  const float* in_b   = (const float*)d_in[3];
  const float* dwa_k  = (const float*)d_in[4];
  const float* dwa_b  = (const float*)d_in[5];
  const float* Amat   = (const float*)d_in[6];
  const float* Bm     = (const float*)d_in[7];
  const float* sym_k  = (const float*)d_in[8];
  const float* sym_b  = (const float*)d_in[9];
  const float* pw_w   = (const float*)d_in[10];
  const float* pw_b   = (const float*)d_in[11];
  const float* ha_w   = (const float*)d_in[12];
  const float* ha_b   = (const float*)d_in[13];
  const float* hb_w   = (const float*)d_in[14];
  const float* hb_b   = (const float*)d_in[15];
  const float* fuse_w = (const float*)d_in[16];
  const float* fuse_b = (const float*)d_in[17];
  const float* out_w  = (const float*)d_in[18];
  const float* out_b  = (const float*)d_in[19];
  float* out = (float*)d_out;

  char* ws = (char*)d_ws;
  const size_t MB = 1u << 20, KB = 1u << 10;
  // Overlay plan (peak 220.63 MB — proven fit at 221):
  //  R0 [0,64):   in_wbf[0,8) + hnorm[8,40)  ->  bsilu  ->  y (concat)
  //  R1 [64,128): val  ->  pwout  ->  y2
  //  R2 [128,192): gate
  //  [192,...): bf16 weights + T1 + cvec + Wp + P
  bf16*  in_wbf  = (bf16*)(ws + 0);
  bf16*  hnorm   = (bf16*)(ws + 8 * MB);
  bf16*  bsilu   = (bf16*)(ws + 0);
  bf16*  ybuf    = (bf16*)(ws + 0);
  bf16*  valp    = (bf16*)(ws + 64 * MB);
  bf16*  pwout   = (bf16*)(ws + 64 * MB);
  bf16*  y2buf   = (bf16*)(ws + 64 * MB);
  bf16*  gatep   = (bf16*)(ws + 128 * MB);
  bf16*  pw_bf   = (bf16*)(ws + 192 * MB);              // 8 MB
  bf16*  fuse_bf = (bf16*)(ws + 200 * MB);              // 8 MB
  bf16*  hb_bf   = (bf16*)(ws + 208 * MB);              // 4 MB
  bf16*  out_bf  = (bf16*)(ws + 212 * MB);              // 4 MB
  float* T1      = (float*)(ws + 216 * MB);             // 64 KB
  float* cvec    = (float*)(ws + 216 * MB + 64 * KB);   // 64 B
  bf16*  Wp      = (bf16*)(ws + 216 * MB + 128 * KB);   // 512 KB
  bf16*  Pbuf    = (bf16*)(ws + 216 * MB + 640 * KB);   // 4 MB

  // weight prep (runs every call; d_ws is re-poisoned before each launch)
  cvt_kernel<<<4096, 256, 0, stream>>>(in_w, in_wbf);
  cvt_kernel<<<4096, 256, 0, stream>>>(pw_w, pw_bf);
  cvt_kernel<<<4096, 256, 0, stream>>>(fuse_w, fuse_bf);
  cvt_kernel<<<2048, 256, 0, stream>>>(hb_w, hb_bf);
  cvt_kernel<<<2048, 256, 0, stream>>>(out_w, out_bf);
  t1_kernel<<<1024, 256, 0, stream>>>(Bm, ha_w, T1);
  cvec_kernel<<<1, 256, 0, stream>>>(dwa_b, Amat, cvec);
  wprep_kernel<<<8, 256, 0, stream>>>(dwa_k, Amat, Wp);

  // 1) rmsnorm
  rmsnorm_kernel<<<MTOK, 256, 0, stream>>>(x, norm_w, hnorm);
  // 2) in-proj GEMM: gate = sigmoid(h[:, :DI]), val = h[:, DI:]
  gemm_bt<EPI_SPLIT><<<dim3(32, 128), 256, 0, stream>>>(
      hnorm, in_wbf, in_b, gatep, valp, nullptr, nullptr, nullptr, 4096, 1024, DI, 0);
  // 3) 9-tap conv + silu  (val -> bsilu, overlays dead in_wbf/hnorm)
  conv_kernel<<<dim3(SEQ / TL2, 2, BATCH), 256, 0, stream>>>(
      valp, sym_k, sym_b, bsilu);
  // 4) skinny P GEMM: P = val @ Wp  (N=128 padded; replaces s16_kernel)
  gemm_bt<EPI_PLAIN><<<dim3(1, 128), 256, 0, stream>>>(
      valp, Wp, nullptr, Pbuf, nullptr, nullptr, nullptr, nullptr, 128, 2048, 128, 0);
  // 5) pw GEMM on silu branch (bsilu -> pwout; pwout overlays dead val)
  gemm_bt<EPI_PLAIN><<<dim3(16, 128), 256, 0, stream>>>(
      bsilu, pw_bf, pw_b, pwout, nullptr, nullptr, nullptr, nullptr, 2048, 2048, 2048, 0);
  // 6) y[:, :1024] = shifted-P @ T1 + ha_b   (y overlays dead bsilu)
  ya_kernel<<<MTOK / 32, 256, 0, stream>>>(Pbuf, T1, cvec, ha_b, ybuf);
  // 7) y[:, 1024:] = hb GEMM (pwout)
  gemm_bt<EPI_PLAIN><<<dim3(8, 128), 256, 0, stream>>>(
      pwout, hb_bf, hb_b, ybuf, nullptr, nullptr, nullptr, nullptr, 1024, 2048, 2048, 1024);
  // 8) fuse GEMM with gate multiply -> y2 (overlays dead pwout)
  gemm_bt<EPI_GATE><<<dim3(16, 128), 256, 0, stream>>>(
      ybuf, fuse_bf, fuse_b, y2buf, nullptr, gatep, nullptr, nullptr, 2048, 2048, 2048, 0);
  // 9) out GEMM + residual -> fp32 d_out
  gemm_bt<EPI_RES><<<dim3(8, 128), 256, 0, stream>>>(
      y2buf, out_bf, out_b, nullptr, nullptr, nullptr, out, x, 1024, 2048, 1024, 0);
}

// Round 4
// 1067.946 us; speedup vs baseline: 1.2030x; 1.0057x over previous
//
#include <hip/hip_runtime.h>
#include <hip/hip_bf16.h>
#include <stdint.h>

typedef __bf16 bf16;
typedef __bf16 bf16x8 __attribute__((ext_vector_type(8)));
typedef __bf16 bf16x4 __attribute__((ext_vector_type(4)));
typedef float  f32x4  __attribute__((ext_vector_type(4)));

#define LDS_PTR(p) ((__attribute__((address_space(3))) uint32_t*)(p))
#define GLB_PTR(p) ((const __attribute__((address_space(1))) uint32_t*)(p))

static constexpr int BATCH = 4, SEQ = 4096, DMODEL = 1024;
static constexpr int DI = 2048;
static constexpr int MTOK = BATCH * SEQ;   // 16384 tokens

// ---------------------------------------------------------------------------
// Generic bf16 MFMA GEMM:  C[m,n] = sum_k X[m,k] * W[n,k]  (+ epilogue)
// 128x128 tile, 4 waves, 4x4 16x16x32 MFMAs/wave (m97 structure).
// GM=8 swizzle: round-robin block->XCD => each XCD sweeps n at fixed m-tile.
// ---------------------------------------------------------------------------
enum { EPI_SPLIT = 0, EPI_PLAIN = 1, EPI_GATEADD = 2, EPI_RES = 3 };

template <int EPI>
__global__ __launch_bounds__(256) void gemm_bt(
    const bf16* __restrict__ Aact, const bf16* __restrict__ W,
    const float* __restrict__ bias,
    bf16* __restrict__ out0, bf16* __restrict__ out1,
    const bf16* __restrict__ gate,
    float* __restrict__ outf, const float* __restrict__ resid,
    int N, int K, int ldC, int col_off)
{
  __shared__ __align__(16) bf16 sA[128 * 32];
  __shared__ __align__(16) bf16 sB[128 * 32];
  const int tid  = threadIdx.x;
  const int nT   = gridDim.x;
  const int lin  = blockIdx.y * nT + blockIdx.x;
  const int grp  = lin / (8 * nT);
  const int within = lin - grp * (8 * nT);
  const int n0   = (within >> 3) * 128;
  const int m0   = (grp * 8 + (within & 7)) * 128;
  const int lane = tid & 63;
  const int wv   = tid >> 6;
  const int wr   = wv >> 1, wc = wv & 1;
  const int l15  = lane & 15, quad = lane >> 4;

  f32x4 acc[4][4];
#pragma unroll
  for (int i = 0; i < 4; ++i)
#pragma unroll
    for (int j = 0; j < 4; ++j) acc[i][j] = (f32x4){0.f, 0.f, 0.f, 0.f};

  const int c0 = tid, c1 = tid + 256;
  const int r0 = c0 >> 2, r1 = c1 >> 2;
  const int cb0 = (c0 & 3) * 16, cb1 = (c1 & 3) * 16;

  const char* gA = (const char*)(Aact + (size_t)m0 * K);
  const char* gW = (const char*)(W + (size_t)n0 * K);

  for (int k0 = 0; k0 < K; k0 += 32) {
    if (k0) __syncthreads();
    __builtin_amdgcn_global_load_lds(GLB_PTR(gA + ((size_t)r0 * K + k0) * 2 + cb0),
                                     LDS_PTR(sA + c0 * 8), 16, 0, 0);
    __builtin_amdgcn_global_load_lds(GLB_PTR(gA + ((size_t)r1 * K + k0) * 2 + cb1),
                                     LDS_PTR(sA + c1 * 8), 16, 0, 0);
    __builtin_amdgcn_global_load_lds(GLB_PTR(gW + ((size_t)r0 * K + k0) * 2 + cb0),
                                     LDS_PTR(sB + c0 * 8), 16, 0, 0);
    __builtin_amdgcn_global_load_lds(GLB_PTR(gW + ((size_t)r1 * K + k0) * 2 + cb1),
                                     LDS_PTR(sB + c1 * 8), 16, 0, 0);
    __syncthreads();

    bf16x8 av[4], bv[4];
#pragma unroll
    for (int t = 0; t < 4; ++t) {
      av[t] = *(const bf16x8*)(sA + (wr * 64 + t * 16 + l15) * 32 + quad * 8);
      bv[t] = *(const bf16x8*)(sB + (wc * 64 + t * 16 + l15) * 32 + quad * 8);
    }
#pragma unroll
    for (int i = 0; i < 4; ++i)
#pragma unroll
      for (int j = 0; j < 4; ++j)
        acc[i][j] = __builtin_amdgcn_mfma_f32_16x16x32_bf16(av[i], bv[j], acc[i][j], 0, 0, 0);
  }

  // epilogue: C/D layout col = lane&15, row = quad*4 + r (m89-verified)
#pragma unroll
  for (int i = 0; i < 4; ++i) {
    const int mbase = m0 + wr * 64 + i * 16 + quad * 4;
#pragma unroll
    for (int j = 0; j < 4; ++j) {
      const int n = n0 + wc * 64 + j * 16 + l15;
      const float bj = bias ? bias[n] : 0.f;
#pragma unroll
      for (int r = 0; r < 4; ++r) {
        const int mm = mbase + r;
        float v = acc[i][j][r] + bj;
        if (EPI == EPI_SPLIT) {
          if (n < DI) out0[(size_t)mm * DI + n] = (bf16)(1.f / (1.f + __expf(-v)));
          else        out1[(size_t)mm * DI + (n - DI)] = (bf16)v;
        } else if (EPI == EPI_PLAIN) {
          out0[(size_t)mm * ldC + col_off + n] = (bf16)v;
        } else if (EPI == EPI_GATEADD) {
          // in-place: out0 holds z_a; y2 = (acc + z_a) * gate overwrites it
          const size_t idx = (size_t)mm * ldC + n;
          float zz = (float)out0[idx];
          float g  = (float)gate[(size_t)mm * DI + n];
          out0[idx] = (bf16)((v + zz) * g);
        } else {  // EPI_RES: fp32 out + residual
          outf[(size_t)mm * ldC + n] = v + resid[(size_t)mm * ldC + n];
        }
      }
    }
  }
}

// ---------------------------------------------------------------------------
// RMSNorm: one block per token row (1024 fp32 -> 1024 bf16)
// ---------------------------------------------------------------------------
__global__ __launch_bounds__(256) void rmsnorm_kernel(
    const float* __restrict__ x, const float* __restrict__ w, bf16* __restrict__ out)
{
  const int row = blockIdx.x;
  const int tid = threadIdx.x;
  const float4 xv = ((const float4*)(x + (size_t)row * DMODEL))[tid];
  float s = xv.x * xv.x + xv.y * xv.y + xv.z * xv.z + xv.w * xv.w;
#pragma unroll
  for (int o = 32; o; o >>= 1) s += __shfl_xor(s, o);
  __shared__ float red[4];
  if ((tid & 63) == 0) red[tid >> 6] = s;
  __syncthreads();
  const float tot = red[0] + red[1] + red[2] + red[3];
  const float scale = rsqrtf(tot * (1.f / DMODEL) + 1e-6f);
  const float4 wv = ((const float4*)w)[tid];
  bf16x4 o4 = { (bf16)(xv.x * wv.x * scale), (bf16)(xv.y * wv.y * scale),
                (bf16)(xv.z * wv.z * scale), (bf16)(xv.w * wv.w * scale) };
  *(bf16x4*)(out + (size_t)row * DMODEL + tid * 4) = o4;
}

// ---------------------------------------------------------------------------
// 9-tap depthwise conv + silu, 4 channels/thread (bf16x4 loads).
// ---------------------------------------------------------------------------
static constexpr int TL2 = 64;
__global__ __launch_bounds__(256) void conv_kernel(
    const bf16* __restrict__ val,
    const float* __restrict__ sym_k, const float* __restrict__ sym_b,
    bf16* __restrict__ bbuf)
{
  const int d  = (blockIdx.y * 256 + threadIdx.x) * 4;
  const int b  = blockIdx.z;
  const int l0 = blockIdx.x * TL2;
  float wk[9][4], bs[4];
#pragma unroll
  for (int j = 0; j < 4; ++j) {
    bs[j] = sym_b[d + j];
#pragma unroll
    for (int k = 0; k < 9; ++k) wk[k][j] = sym_k[(d + j) * 9 + k];
  }
  const bf16* base = val + (size_t)b * SEQ * DI + d;

  float win[9][4];
#pragma unroll
  for (int j = 0; j < 8; ++j) {
    const int xr = l0 + j - 4;
    if (xr >= 0 && xr < SEQ) {
      bf16x4 v = *(const bf16x4*)(base + (size_t)xr * DI);
#pragma unroll
      for (int c = 0; c < 4; ++c) win[j][c] = (float)v[c];
    } else {
#pragma unroll
      for (int c = 0; c < 4; ++c) win[j][c] = 0.f;
    }
  }
  for (int t = 0; t < TL2; ++t) {
    const int xf = l0 + t + 4;
    if (xf < SEQ) {
      bf16x4 v = *(const bf16x4*)(base + (size_t)xf * DI);
#pragma unroll
      for (int c = 0; c < 4; ++c) win[8][c] = (float)v[c];
    } else {
#pragma unroll
      for (int c = 0; c < 4; ++c) win[8][c] = 0.f;
    }
    float sb[4];
#pragma unroll
    for (int c = 0; c < 4; ++c) sb[c] = bs[c];
#pragma unroll
    for (int k = 0; k < 9; ++k)
#pragma unroll
      for (int c = 0; c < 4; ++c) sb[c] += win[k][c] * wk[k][c];
    bf16x4 o;
#pragma unroll
    for (int c = 0; c < 4; ++c) o[c] = (bf16)(sb[c] / (1.f + __expf(-sb[c])));
    *(bf16x4*)(bbuf + ((size_t)b * SEQ + l0 + t) * DI + d) = o;
#pragma unroll
    for (int k = 0; k < 8; ++k)
#pragma unroll
      for (int c = 0; c < 4; ++c) win[k][c] = win[k + 1][c];
  }
}

// ---------------------------------------------------------------------------
// Wp[n][d] = dwa_k[d,k] * A[d,s] for n = k*16+s (n<64); 0 for n in [64,128)
// ---------------------------------------------------------------------------
__global__ __launch_bounds__(256) void wprep_kernel(
    const float* __restrict__ dwa_k, const float* __restrict__ A, bf16* __restrict__ Wp)
{
  const int d = blockIdx.x * 256 + threadIdx.x;
  float kk[4], av[16];
#pragma unroll
  for (int k = 0; k < 4; ++k) kk[k] = dwa_k[d * 4 + k];
#pragma unroll
  for (int s = 0; s < 16; ++s) av[s] = A[d * 16 + s];
#pragma unroll
  for (int k = 0; k < 4; ++k)
#pragma unroll
    for (int s = 0; s < 16; ++s)
      Wp[(size_t)(k * 16 + s) * 2048 + d] = (bf16)(kk[k] * av[s]);
  for (int n = 64; n < 128; ++n) Wp[(size_t)n * 2048 + d] = (bf16)0.f;
}

// cvec[s] = sum_d dwa_b[d] * A[d,s]
__global__ __launch_bounds__(256) void cvec_kernel(
    const float* __restrict__ dwa_b, const float* __restrict__ A, float* __restrict__ cvec)
{
  const int tid = threadIdx.x;
  float acc[16];
#pragma unroll
  for (int s = 0; s < 16; ++s) acc[s] = 0.f;
  for (int d = tid; d < 2048; d += 256) {
    const float w = dwa_b[d];
#pragma unroll
    for (int s = 0; s < 16; ++s) acc[s] += w * A[d * 16 + s];
  }
  const int lane = tid & 63, wv = tid >> 6;
  __shared__ float red[4][16];
#pragma unroll
  for (int s = 0; s < 16; ++s) {
    float v = acc[s];
#pragma unroll
    for (int off = 32; off; off >>= 1) v += __shfl_xor(v, off);
    if (lane == s) red[wv][s] = v;
  }
  __syncthreads();
  if (tid < 16) cvec[tid] = red[0][tid] + red[1][tid] + red[2][tid] + red[3][tid];
}

// ---------------------------------------------------------------------------
// T1[s,o] = sum_d Bm[s,d] * ha_w[o,d]   (16 x 1024). One block per o.
// ---------------------------------------------------------------------------
__global__ __launch_bounds__(256) void t1_kernel(
    const float* __restrict__ Bm, const float* __restrict__ ha_w, float* __restrict__ T1)
{
  const int o = blockIdx.x, tid = threadIdx.x;
  float acc[16];
#pragma unroll
  for (int s = 0; s < 16; ++s) acc[s] = 0.f;
  for (int d = tid; d < 2048; d += 256) {
    const float w = ha_w[(size_t)o * 2048 + d];
#pragma unroll
    for (int s = 0; s < 16; ++s) acc[s] += Bm[s * 2048 + d] * w;
  }
  const int lane = tid & 63, wv = tid >> 6;
  __shared__ float red[4][16];
#pragma unroll
  for (int s = 0; s < 16; ++s) {
    float v = acc[s];
#pragma unroll
    for (int off = 32; off; off >>= 1) v += __shfl_xor(v, off);
    if (lane == s) red[wv][s] = v;
  }
  __syncthreads();
  if (tid < 16)
    T1[tid * 1024 + o] = red[0][tid] + red[1][tid] + red[2][tid] + red[3][tid];
}

// T2t[n][s] = sum_{o<1024} T1[s,o] * fuse_w[n,o]   (transposed T1@F_a^T)
__global__ __launch_bounds__(256) void t2t_kernel(
    const float* __restrict__ T1, const float* __restrict__ fuse_w, float* __restrict__ T2t)
{
  const int tid = threadIdx.x;
  const int n = blockIdx.x * 16 + (tid >> 4);
  const int s = tid & 15;
  const float* fr = fuse_w + (size_t)n * 2048;
  const float* tr = T1 + s * 1024;
  float acc = 0.f;
  for (int o = 0; o < 1024; o += 4) {
    float4 f = *(const float4*)(fr + o);
    float4 t = *(const float4*)(tr + o);
    acc += f.x * t.x + f.y * t.y + f.z * t.z + f.w * t.w;
  }
  T2t[n * 16 + s] = acc;
}

// b_H[o] = hb_b[o] + sum_c hb_w[o,c] * pw_b[c]
__global__ __launch_bounds__(256) void bh_kernel(
    const float* __restrict__ hb_w, const float* __restrict__ pw_b,
    const float* __restrict__ hb_b, float* __restrict__ b_H)
{
  const int o = blockIdx.x * 256 + threadIdx.x;
  float acc = hb_b[o];
  const float* hr = hb_w + (size_t)o * 2048;
  for (int c = 0; c < 2048; c += 4) {
    float4 h = *(const float4*)(hr + c);
    float4 p = *(const float4*)(pw_b + c);
    acc += h.x * p.x + h.y * p.y + h.z * p.z + h.w * p.w;
  }
  b_H[o] = acc;
}

// bias_z[n] = fuse_b[n] + sum_o ha_b[o]*fuse_w[n,o] + sum_o b_H[o]*fuse_w[n,1024+o]
__global__ __launch_bounds__(256) void biasz_kernel(
    const float* __restrict__ fuse_w, const float* __restrict__ fuse_b,
    const float* __restrict__ ha_b, const float* __restrict__ b_H,
    float* __restrict__ bias_z)
{
  const int n = blockIdx.x * 256 + threadIdx.x;
  float acc = fuse_b[n];
  const float* fr = fuse_w + (size_t)n * 2048;
  for (int o = 0; o < 1024; o += 4) {
    float4 fa = *(const float4*)(fr + o);
    float4 fb = *(const float4*)(fr + 1024 + o);
    float4 ha = *(const float4*)(ha_b + o);
    float4 bh = *(const float4*)(b_H + o);
    acc += fa.x * ha.x + fa.y * ha.y + fa.z * ha.z + fa.w * ha.w;
    acc += fb.x * bh.x + fb.y * bh.y + fb.z * bh.z + fb.w * bh.w;
  }
  bias_z[n] = acc;
}

// pwT_bf[d][c] = (bf16)pw_w[c][d]   (2048x2048 transpose via LDS)
__global__ __launch_bounds__(256) void transpose_kernel(
    const float* __restrict__ in, bf16* __restrict__ out)
{
  __shared__ float s[32][33];
  const int tid = threadIdx.x;
  const int r = tid >> 5, x = tid & 31;
  const int c0 = blockIdx.y * 32, d0 = blockIdx.x * 32;
#pragma unroll
  for (int rr = r; rr < 32; rr += 8)
    s[rr][x] = in[(size_t)(c0 + rr) * 2048 + d0 + x];
  __syncthreads();
#pragma unroll
  for (int rr = r; rr < 32; rr += 8)
    out[(size_t)(d0 + rr) * 2048 + c0 + x] = (bf16)s[x][rr];
}

// Fb_p[n][o] = (bf16)fuse_w[n][1024+o]   (packed F_b, 2048x1024)
__global__ __launch_bounds__(256) void fbcopy_kernel(
    const float* __restrict__ fuse_w, bf16* __restrict__ Fb)
{
  const int idx = blockIdx.x * 256 + threadIdx.x;
  const int n = idx >> 8, o4 = idx & 255;
  float4 v = ((const float4*)(fuse_w + (size_t)n * 2048 + 1024))[o4];
  bf16x4 o = { (bf16)v.x, (bf16)v.y, (bf16)v.z, (bf16)v.w };
  *(bf16x4*)(Fb + (size_t)n * 1024 + o4 * 4) = o;
}

// ---------------------------------------------------------------------------
// z_a[m,n] = bias_z[n] + sum_s s16[m,s]*T2t[n,s], s16 from P-shifts + cvec.
// One block = 32 tokens x all 2048 cols; T2t cols held in registers.
// ---------------------------------------------------------------------------
__global__ __launch_bounds__(256) void za_kernel(
    const bf16* __restrict__ P, const float* __restrict__ T2t,
    const float* __restrict__ cvec, const float* __restrict__ bias_z,
    bf16* __restrict__ z)
{
  __shared__ float s16t[32][16];
  const int tid = threadIdx.x;
  const int tok0 = blockIdx.x * 32;
  for (int p = tid; p < 512; p += 256) {
    const int t = p >> 4, s = p & 15;
    const int tok = tok0 + t;
    const int l = tok & (SEQ - 1), bb = tok >> 12;
    float acc = cvec[s];
#pragma unroll
    for (int k = 0; k < 4; ++k) {
      const int r = l - 1 + k;
      if ((unsigned)r < (unsigned)SEQ)
        acc += (float)P[((size_t)bb * SEQ + r) * 128 + k * 16 + s];
    }
    s16t[t][s] = acc;
  }
  const int c0 = tid * 8;
  float t2[8][16], bz[8];
#pragma unroll
  for (int j = 0; j < 8; ++j) {
    bz[j] = bias_z[c0 + j];
#pragma unroll
    for (int q = 0; q < 4; ++q) {
      float4 v = ((const float4*)(T2t + (size_t)(c0 + j) * 16))[q];
      t2[j][q * 4 + 0] = v.x; t2[j][q * 4 + 1] = v.y;
      t2[j][q * 4 + 2] = v.z; t2[j][q * 4 + 3] = v.w;
    }
  }
  __syncthreads();
  for (int t = 0; t < 32; ++t) {
    float sv[16];
#pragma unroll
    for (int s = 0; s < 16; ++s) sv[s] = s16t[t][s];
    bf16x8 o;
#pragma unroll
    for (int j = 0; j < 8; ++j) {
      float a = bz[j];
#pragma unroll
      for (int s = 0; s < 16; ++s) a += sv[s] * t2[j][s];
      o[j] = (bf16)a;
    }
    *(bf16x8*)(z + (size_t)(tok0 + t) * 2048 + c0) = o;
  }
}

// ---------------------------------------------------------------------------
// fp32 -> bf16 conversion
// ---------------------------------------------------------------------------
__global__ __launch_bounds__(256) void cvt_kernel(
    const float* __restrict__ in, bf16* __restrict__ out)
{
  const size_t i = (size_t)blockIdx.x * 256 + threadIdx.x;
  const float4 v = ((const float4*)in)[i];
  bf16x4 o4 = { (bf16)v.x, (bf16)v.y, (bf16)v.z, (bf16)v.w };
  *(bf16x4*)(out + 4 * i) = o4;
}

// ---------------------------------------------------------------------------
extern "C" void kernel_launch(void* const* d_in, const int* in_sizes, int n_in,
                              void* d_out, int out_size, void* d_ws, size_t ws_size,
                              hipStream_t stream)
{
  const float* x      = (const float*)d_in[0];
  const float* norm_w = (const float*)d_in[1];
  const float* in_w   = (const float*)d_in[2];
  const float* in_b   = (const float*)d_in[3];
  const float* dwa_k  = (const float*)d_in[4];
  const float* dwa_b  = (const float*)d_in[5];
  const float* Amat   = (const float*)d_in[6];
  const float* Bm     = (const float*)d_in[7];
  const float* sym_k  = (const float*)d_in[8];
  const float* sym_b  = (const float*)d_in[9];
  const float* pw_w   = (const float*)d_in[10];
  const float* pw_b   = (const float*)d_in[11];
  const float* ha_w   = (const float*)d_in[12];
  const float* ha_b   = (const float*)d_in[13];
  const float* hb_w   = (const float*)d_in[14];
  const float* hb_b   = (const float*)d_in[15];
  const float* fuse_w = (const float*)d_in[16];
  const float* fuse_b = (const float*)d_in[17];
  const float* out_w  = (const float*)d_in[18];
  const float* out_b  = (const float*)d_in[19];
  float* out = (float*)d_out;

  char* ws = (char*)d_ws;
  const size_t MB = 1u << 20, KB = 1u << 10;
  // Overlay plan (peak ~217 MB):
  //  R0 [0,64):   in_wbf[0,8) + hnorm[8,40)  ->  bsilu
  //  R1 [64,128): val  ->  z_a  ->  y2 (B-GEMM in-place)
  //  R2 [128,192): gate
  //  [192,...): Pbuf, folded weights, small vecs
  bf16*  in_wbf  = (bf16*)(ws + 0);
  bf16*  hnorm   = (bf16*)(ws + 8 * MB);
  bf16*  bsilu   = (bf16*)(ws + 0);
  bf16*  valp    = (bf16*)(ws + 64 * MB);
  bf16*  zbuf    = (bf16*)(ws + 64 * MB);   // z_a then y2 (in-place)
  bf16*  gatep   = (bf16*)(ws + 128 * MB);
  bf16*  Pbuf    = (bf16*)(ws + 192 * MB);              // 4 MB
  bf16*  pwT_bf  = (bf16*)(ws + 196 * MB);              // 8 MB (dead after Ht)
  bf16*  WB_bf   = (bf16*)(ws + 196 * MB);              // 8 MB (overlays pwT)
  bf16*  hb_bf   = (bf16*)(ws + 204 * MB);              // 4 MB (dead after Ht)
  bf16*  Fb_bf   = (bf16*)(ws + 204 * MB);              // 4 MB (overlays hb_bf)
  bf16*  Ht_bf   = (bf16*)(ws + 208 * MB);              // 4 MB
  bf16*  out_bf  = (bf16*)(ws + 212 * MB);              // 4 MB
  float* T1      = (float*)(ws + 216 * MB);             // 64 KB
  float* cvec    = (float*)(ws + 216 * MB + 64 * KB);   // 64 B
  float* b_H     = (float*)(ws + 216 * MB + 68 * KB);   // 4 KB
  float* bias_z  = (float*)(ws + 216 * MB + 72 * KB);   // 8 KB
  bf16*  Wp      = (bf16*)(ws + 216 * MB + 80 * KB);    // 512 KB
  float* T2t     = (float*)(ws + 216 * MB + 592 * KB);  // 128 KB

  // ---- weight prep (every call; ws re-poisoned before each launch) ----
  cvt_kernel<<<4096, 256, 0, stream>>>(in_w, in_wbf);
  cvt_kernel<<<2048, 256, 0, stream>>>(hb_w, hb_bf);
  cvt_kernel<<<2048, 256, 0, stream>>>(out_w, out_bf);
  transpose_kernel<<<dim3(64, 64), 256, 0, stream>>>(pw_w, pwT_bf);
  // Ht[d,o] = sum_c pw_w[c,d]*hb_w[o,c]  (= (hb_w@pw_w)^T)
  gemm_bt<EPI_PLAIN><<<dim3(8, 16), 256, 0, stream>>>(
      pwT_bf, hb_bf, nullptr, Ht_bf, nullptr, nullptr, nullptr, nullptr, 1024, 2048, 1024, 0);
  fbcopy_kernel<<<2048, 256, 0, stream>>>(fuse_w, Fb_bf);
  // W_B[n,d] = sum_o F_b[n,o]*Ht[d,o]  (= F_b@hb_w@pw_w)
  gemm_bt<EPI_PLAIN><<<dim3(16, 16), 256, 0, stream>>>(
      Fb_bf, Ht_bf, nullptr, WB_bf, nullptr, nullptr, nullptr, nullptr, 2048, 1024, 2048, 0);
  t1_kernel<<<1024, 256, 0, stream>>>(Bm, ha_w, T1);
  t2t_kernel<<<128, 256, 0, stream>>>(T1, fuse_w, T2t);
  cvec_kernel<<<1, 256, 0, stream>>>(dwa_b, Amat, cvec);
  wprep_kernel<<<8, 256, 0, stream>>>(dwa_k, Amat, Wp);
  bh_kernel<<<4, 256, 0, stream>>>(hb_w, pw_b, hb_b, b_H);
  biasz_kernel<<<8, 256, 0, stream>>>(fuse_w, fuse_b, ha_b, b_H, bias_z);

  // ---- main chain ----
  rmsnorm_kernel<<<MTOK, 256, 0, stream>>>(x, norm_w, hnorm);
  // in-proj: gate = sigmoid(h[:, :DI]), val = h[:, DI:]
  gemm_bt<EPI_SPLIT><<<dim3(32, 128), 256, 0, stream>>>(
      hnorm, in_wbf, in_b, gatep, valp, nullptr, nullptr, nullptr, 4096, 1024, DI, 0);
  // 9-tap conv + silu (val -> bsilu, overlays dead in_wbf/hnorm)
  conv_kernel<<<dim3(SEQ / TL2, 2, BATCH), 256, 0, stream>>>(
      valp, sym_k, sym_b, bsilu);
  // skinny P GEMM: P = val @ Wp^T  (N=128 padded)
  gemm_bt<EPI_PLAIN><<<dim3(1, 128), 256, 0, stream>>>(
      valp, Wp, nullptr, Pbuf, nullptr, nullptr, nullptr, nullptr, 128, 2048, 128, 0);
  // z_a = s16 @ T2 + bias_z  (writes R1, val now dead)
  za_kernel<<<MTOK / 32, 256, 0, stream>>>(Pbuf, T2t, cvec, bias_z, zbuf);
  // B-GEMM: y2 = gate * (bsilu @ W_B^T + z_a)   [in-place over zbuf]
  gemm_bt<EPI_GATEADD><<<dim3(16, 128), 256, 0, stream>>>(
      bsilu, WB_bf, nullptr, zbuf, nullptr, gatep, nullptr, nullptr, 2048, 2048, 2048, 0);
  // out GEMM + residual -> fp32 d_out
  gemm_bt<EPI_RES><<<dim3(8, 128), 256, 0, stream>>>(
      zbuf, out_bf, out_b, nullptr, nullptr, nullptr, out, x, 1024, 2048, 1024, 0);
}

// Round 5
// 919.901 us; speedup vs baseline: 1.3966x; 1.1609x over previous
//
#include <hip/hip_runtime.h>
#include <hip/hip_bf16.h>
#include <stdint.h>

typedef __bf16 bf16;
typedef __bf16 bf16x8 __attribute__((ext_vector_type(8)));
typedef __bf16 bf16x4 __attribute__((ext_vector_type(4)));
typedef float  f32x4  __attribute__((ext_vector_type(4)));

#define LDS_PTR(p) ((__attribute__((address_space(3))) uint32_t*)(p))
#define GLB_PTR(p) ((const __attribute__((address_space(1))) uint32_t*)(p))

static constexpr int BATCH = 4, SEQ = 4096, DMODEL = 1024;
static constexpr int DI = 2048;
static constexpr int MTOK = BATCH * SEQ;   // 16384 tokens

// ---------------------------------------------------------------------------
// bf16 MFMA GEMM:  C[m,n] = sum_k X[m,k] * W[n,k]  (+ epilogue)
// 128x128 tile, BK=64 (half the barrier drains of BK=32), 4 waves,
// 4x4 16x16x32 MFMAs per wave per K-half. LDS uses an XOR swizzle
// (slot = r*8 + (cc ^ (r&7))) so ds_read_b128 fragment reads are
// bank-conflict-free; legal with global_load_lds because the per-lane
// GLOBAL source is permuted, not the LDS destination.
// ---------------------------------------------------------------------------
enum { EPI_SPLIT = 0, EPI_PLAIN = 1, EPI_GATEADD = 2, EPI_RES = 3 };

template <int EPI, bool SPLITK = false>
__global__ __launch_bounds__(256) void gemm_bt(
    const bf16* __restrict__ Aact, const bf16* __restrict__ W,
    const float* __restrict__ bias,
    bf16* __restrict__ out0, bf16* __restrict__ out1,
    const bf16* __restrict__ gate,
    float* __restrict__ outf, const float* __restrict__ resid,
    int N, int K, int ldC, int col_off)
{
  __shared__ __align__(16) bf16 sA[128 * 64];
  __shared__ __align__(16) bf16 sB[128 * 64];
  const int tid  = threadIdx.x;
  int n0, m0, kbeg, kend;
  size_t out_off = 0;
  if (SPLITK) {
    n0 = 0; m0 = blockIdx.y * 128;
    const int kh = K / gridDim.x;
    kbeg = blockIdx.x * kh; kend = kbeg + kh;
    out_off = (size_t)blockIdx.x * ((size_t)MTOK * 128);
  } else {
    // GM=8 swizzle (gridDim.y multiple of 8): XCD sweeps n at fixed m-group
    const int nT  = gridDim.x;
    const int lin = blockIdx.y * nT + blockIdx.x;
    const int grp = lin / (8 * nT);
    const int within = lin - grp * (8 * nT);
    n0 = (within >> 3) * 128;
    m0 = (grp * 8 + (within & 7)) * 128;
    kbeg = 0; kend = K;
  }
  const int lane = tid & 63;
  const int wv   = tid >> 6;
  const int wr   = wv >> 1, wc = wv & 1;
  const int l15  = lane & 15, quad = lane >> 4;

  f32x4 acc[4][4];
#pragma unroll
  for (int i = 0; i < 4; ++i)
#pragma unroll
    for (int j = 0; j < 4; ++j) acc[i][j] = (f32x4){0.f, 0.f, 0.f, 0.f};

  // staging: 1024 16B-chunks per 16KB tile; 4 slots per thread.
  // slot s -> row r = s>>3, slot-in-row sc = s&7, global chunk cc = sc^(r&7)
  int rr[4], cb[4];
#pragma unroll
  for (int j = 0; j < 4; ++j) {
    const int s = tid + j * 256;
    rr[j] = s >> 3;
    cb[j] = ((s & 7) ^ (rr[j] & 7)) * 16;
  }

  const char* gA = (const char*)(Aact + (size_t)m0 * K);
  const char* gW = (const char*)(W + (size_t)n0 * K);

  for (int k0 = kbeg; k0 < kend; k0 += 64) {
    if (k0 != kbeg) __syncthreads();
#pragma unroll
    for (int j = 0; j < 4; ++j)
      __builtin_amdgcn_global_load_lds(GLB_PTR(gA + ((size_t)rr[j] * K + k0) * 2 + cb[j]),
                                       LDS_PTR(sA + (tid + j * 256) * 8), 16, 0, 0);
#pragma unroll
    for (int j = 0; j < 4; ++j)
      __builtin_amdgcn_global_load_lds(GLB_PTR(gW + ((size_t)rr[j] * K + k0) * 2 + cb[j]),
                                       LDS_PTR(sB + (tid + j * 256) * 8), 16, 0, 0);
    __syncthreads();

#pragma unroll
    for (int h = 0; h < 2; ++h) {
      bf16x8 av[4], bv[4];
#pragma unroll
      for (int t = 0; t < 4; ++t) {
        const int Ra = wr * 64 + t * 16 + l15;
        const int Rb = wc * 64 + t * 16 + l15;
        const int cc = h * 4 + quad;
        av[t] = *(const bf16x8*)(sA + (Ra * 8 + (cc ^ (Ra & 7))) * 8);
        bv[t] = *(const bf16x8*)(sB + (Rb * 8 + (cc ^ (Rb & 7))) * 8);
      }
#pragma unroll
      for (int i = 0; i < 4; ++i)
#pragma unroll
        for (int j = 0; j < 4; ++j)
          acc[i][j] = __builtin_amdgcn_mfma_f32_16x16x32_bf16(av[i], bv[j], acc[i][j], 0, 0, 0);
    }
  }

  bf16* o0 = out0 + out_off;
  // epilogue: C/D layout col = lane&15, row = quad*4 + r (m89-verified)
#pragma unroll
  for (int i = 0; i < 4; ++i) {
    const int mbase = m0 + wr * 64 + i * 16 + quad * 4;
#pragma unroll
    for (int j = 0; j < 4; ++j) {
      const int n = n0 + wc * 64 + j * 16 + l15;
      const float bj = bias ? bias[n] : 0.f;
#pragma unroll
      for (int r = 0; r < 4; ++r) {
        const int mm = mbase + r;
        float v = acc[i][j][r] + bj;
        if (EPI == EPI_SPLIT) {
          if (n < DI) o0[(size_t)mm * DI + n] = (bf16)(1.f / (1.f + __expf(-v)));
          else        out1[(size_t)mm * DI + (n - DI)] = (bf16)v;
        } else if (EPI == EPI_PLAIN) {
          o0[(size_t)mm * ldC + col_off + n] = (bf16)v;
        } else if (EPI == EPI_GATEADD) {
          const size_t idx = (size_t)mm * ldC + n;
          float zz = (float)o0[idx];
          float g  = (float)gate[(size_t)mm * DI + n];
          o0[idx] = (bf16)((v + zz) * g);
        } else {  // EPI_RES: fp32 out + residual
          outf[(size_t)mm * ldC + n] = v + resid[(size_t)mm * ldC + n];
        }
      }
    }
  }
}

// ---------------------------------------------------------------------------
// RMSNorm: one block per token row (1024 fp32 -> 1024 bf16)
// ---------------------------------------------------------------------------
__global__ __launch_bounds__(256) void rmsnorm_kernel(
    const float* __restrict__ x, const float* __restrict__ w, bf16* __restrict__ out)
{
  const int row = blockIdx.x;
  const int tid = threadIdx.x;
  const float4 xv = ((const float4*)(x + (size_t)row * DMODEL))[tid];
  float s = xv.x * xv.x + xv.y * xv.y + xv.z * xv.z + xv.w * xv.w;
#pragma unroll
  for (int o = 32; o; o >>= 1) s += __shfl_xor(s, o);
  __shared__ float red[4];
  if ((tid & 63) == 0) red[tid >> 6] = s;
  __syncthreads();
  const float tot = red[0] + red[1] + red[2] + red[3];
  const float scale = rsqrtf(tot * (1.f / DMODEL) + 1e-6f);
  const float4 wv = ((const float4*)w)[tid];
  bf16x4 o4 = { (bf16)(xv.x * wv.x * scale), (bf16)(xv.y * wv.y * scale),
                (bf16)(xv.z * wv.z * scale), (bf16)(xv.w * wv.w * scale) };
  *(bf16x4*)(out + (size_t)row * DMODEL + tid * 4) = o4;
}

// ---------------------------------------------------------------------------
// 9-tap depthwise conv + silu, 4 channels/thread (bf16x4 loads).
// ---------------------------------------------------------------------------
static constexpr int TL2 = 64;
__global__ __launch_bounds__(256) void conv_kernel(
    const bf16* __restrict__ val,
    const float* __restrict__ sym_k, const float* __restrict__ sym_b,
    bf16* __restrict__ bbuf)
{
  const int d  = (blockIdx.y * 256 + threadIdx.x) * 4;
  const int b  = blockIdx.z;
  const int l0 = blockIdx.x * TL2;
  float wk[9][4], bs[4];
#pragma unroll
  for (int j = 0; j < 4; ++j) {
    bs[j] = sym_b[d + j];
#pragma unroll
    for (int k = 0; k < 9; ++k) wk[k][j] = sym_k[(d + j) * 9 + k];
  }
  const bf16* base = val + (size_t)b * SEQ * DI + d;

  float win[9][4];
#pragma unroll
  for (int j = 0; j < 8; ++j) {
    const int xr = l0 + j - 4;
    if (xr >= 0 && xr < SEQ) {
      bf16x4 v = *(const bf16x4*)(base + (size_t)xr * DI);
#pragma unroll
      for (int c = 0; c < 4; ++c) win[j][c] = (float)v[c];
    } else {
#pragma unroll
      for (int c = 0; c < 4; ++c) win[j][c] = 0.f;
    }
  }
  for (int t = 0; t < TL2; ++t) {
    const int xf = l0 + t + 4;
    if (xf < SEQ) {
      bf16x4 v = *(const bf16x4*)(base + (size_t)xf * DI);
#pragma unroll
      for (int c = 0; c < 4; ++c) win[8][c] = (float)v[c];
    } else {
#pragma unroll
      for (int c = 0; c < 4; ++c) win[8][c] = 0.f;
    }
    float sb[4];
#pragma unroll
    for (int c = 0; c < 4; ++c) sb[c] = bs[c];
#pragma unroll
    for (int k = 0; k < 9; ++k)
#pragma unroll
      for (int c = 0; c < 4; ++c) sb[c] += win[k][c] * wk[k][c];
    bf16x4 o;
#pragma unroll
    for (int c = 0; c < 4; ++c) o[c] = (bf16)(sb[c] / (1.f + __expf(-sb[c])));
    *(bf16x4*)(bbuf + ((size_t)b * SEQ + l0 + t) * DI + d) = o;
#pragma unroll
    for (int k = 0; k < 8; ++k)
#pragma unroll
      for (int c = 0; c < 4; ++c) win[k][c] = win[k + 1][c];
  }
}

// ---------------------------------------------------------------------------
// prep_cvt: merged fp32->bf16 conversions (in_w, hb_w, out_w)
// grid = 4096 + 2048 + 2048 = 8192 blocks
// ---------------------------------------------------------------------------
__global__ __launch_bounds__(256) void prep_cvt_kernel(
    const float* __restrict__ in_w, const float* __restrict__ hb_w,
    const float* __restrict__ out_w,
    bf16* __restrict__ in_wbf, bf16* __restrict__ hb_bf, bf16* __restrict__ out_bf)
{
  const int b = blockIdx.x;
  const float* src; bf16* dst; size_t i;
  if (b < 4096)      { src = in_w;  dst = in_wbf; i = (size_t)b * 256 + threadIdx.x; }
  else if (b < 6144) { src = hb_w;  dst = hb_bf;  i = (size_t)(b - 4096) * 256 + threadIdx.x; }
  else               { src = out_w; dst = out_bf; i = (size_t)(b - 6144) * 256 + threadIdx.x; }
  const float4 v = ((const float4*)src)[i];
  bf16x4 o4 = { (bf16)v.x, (bf16)v.y, (bf16)v.z, (bf16)v.w };
  *(bf16x4*)(dst + 4 * i) = o4;
}

// pwT_bf[d][c] = (bf16)pw_w[c][d]   (2048x2048 transpose via LDS)
__global__ __launch_bounds__(256) void transpose_kernel(
    const float* __restrict__ in, bf16* __restrict__ out)
{
  __shared__ float s[32][33];
  const int tid = threadIdx.x;
  const int r = tid >> 5, x = tid & 31;
  const int c0 = blockIdx.y * 32, d0 = blockIdx.x * 32;
#pragma unroll
  for (int rr = r; rr < 32; rr += 8)
    s[rr][x] = in[(size_t)(c0 + rr) * 2048 + d0 + x];
  __syncthreads();
#pragma unroll
  for (int rr = r; rr < 32; rr += 8)
    out[(size_t)(d0 + rr) * 2048 + c0 + x] = (bf16)s[x][rr];
}

// ---------------------------------------------------------------------------
// prep_small: t1 (1024) | cvec (1) | bh (4) | wprep (8) | fbcopy (2048)
// total grid = 3085 blocks. Runs AFTER Ht-GEMM (Fb_bf overlays hb_bf).
// ---------------------------------------------------------------------------
__global__ __launch_bounds__(256) void prep_small_kernel(
    const float* __restrict__ Bm, const float* __restrict__ ha_w,
    const float* __restrict__ dwa_b, const float* __restrict__ dwa_k,
    const float* __restrict__ A,
    const float* __restrict__ hb_w, const float* __restrict__ pw_b,
    const float* __restrict__ hb_b, const float* __restrict__ fuse_w,
    float* __restrict__ T1, float* __restrict__ cvec, float* __restrict__ b_H,
    bf16* __restrict__ Wp, bf16* __restrict__ Fb)
{
  const int b = blockIdx.x, tid = threadIdx.x;
  __shared__ float red[4][16];
  if (b < 1024) {
    // T1[s,o] = sum_d Bm[s,d] * ha_w[o,d]
    const int o = b;
    float acc[16];
#pragma unroll
    for (int s = 0; s < 16; ++s) acc[s] = 0.f;
    for (int d = tid; d < 2048; d += 256) {
      const float w = ha_w[(size_t)o * 2048 + d];
#pragma unroll
      for (int s = 0; s < 16; ++s) acc[s] += Bm[s * 2048 + d] * w;
    }
    const int lane = tid & 63, wv = tid >> 6;
#pragma unroll
    for (int s = 0; s < 16; ++s) {
      float v = acc[s];
#pragma unroll
      for (int off = 32; off; off >>= 1) v += __shfl_xor(v, off);
      if (lane == s) red[wv][s] = v;
    }
    __syncthreads();
    if (tid < 16)
      T1[tid * 1024 + o] = red[0][tid] + red[1][tid] + red[2][tid] + red[3][tid];
  } else if (b == 1024) {
    // cvec[s] = sum_d dwa_b[d] * A[d,s]
    float acc[16];
#pragma unroll
    for (int s = 0; s < 16; ++s) acc[s] = 0.f;
    for (int d = tid; d < 2048; d += 256) {
      const float w = dwa_b[d];
#pragma unroll
      for (int s = 0; s < 16; ++s) acc[s] += w * A[d * 16 + s];
    }
    const int lane = tid & 63, wv = tid >> 6;
#pragma unroll
    for (int s = 0; s < 16; ++s) {
      float v = acc[s];
#pragma unroll
      for (int off = 32; off; off >>= 1) v += __shfl_xor(v, off);
      if (lane == s) red[wv][s] = v;
    }
    __syncthreads();
    if (tid < 16) cvec[tid] = red[0][tid] + red[1][tid] + red[2][tid] + red[3][tid];
  } else if (b < 1029) {
    // b_H[o] = hb_b[o] + sum_c hb_w[o,c] * pw_b[c]
    const int o = (b - 1025) * 256 + tid;
    float acc = hb_b[o];
    const float* hr = hb_w + (size_t)o * 2048;
    for (int c = 0; c < 2048; c += 4) {
      float4 h = *(const float4*)(hr + c);
      float4 p = *(const float4*)(pw_b + c);
      acc += h.x * p.x + h.y * p.y + h.z * p.z + h.w * p.w;
    }
    b_H[o] = acc;
  } else if (b < 1037) {
    // Wp[n][d] = dwa_k[d,k]*A[d,s], n=k*16+s (n<64); 0 for n in [64,128)
    const int d = (b - 1029) * 256 + tid;
    float kk[4], av[16];
#pragma unroll
    for (int k = 0; k < 4; ++k) kk[k] = dwa_k[d * 4 + k];
#pragma unroll
    for (int s = 0; s < 16; ++s) av[s] = A[d * 16 + s];
#pragma unroll
    for (int k = 0; k < 4; ++k)
#pragma unroll
      for (int s = 0; s < 16; ++s)
        Wp[(size_t)(k * 16 + s) * 2048 + d] = (bf16)(kk[k] * av[s]);
    for (int n = 64; n < 128; ++n) Wp[(size_t)n * 2048 + d] = (bf16)0.f;
  } else {
    // Fb[n][o] = (bf16)fuse_w[n][1024+o]
    const int idx = (b - 1037) * 256 + tid;
    const int n = idx >> 8, o4 = idx & 255;
    float4 v = ((const float4*)(fuse_w + (size_t)n * 2048 + 1024))[o4];
    bf16x4 o = { (bf16)v.x, (bf16)v.y, (bf16)v.z, (bf16)v.w };
    *(bf16x4*)(Fb + (size_t)n * 1024 + o4 * 4) = o;
  }
}

// ---------------------------------------------------------------------------
// prep_fuse: t2t (128 blocks) | biasz (8 blocks). Needs T1 and b_H.
// ---------------------------------------------------------------------------
__global__ __launch_bounds__(256) void prep_fuse_kernel(
    const float* __restrict__ T1, const float* __restrict__ fuse_w,
    const float* __restrict__ fuse_b, const float* __restrict__ ha_b,
    const float* __restrict__ b_H,
    float* __restrict__ T2t, float* __restrict__ bias_z)
{
  const int b = blockIdx.x, tid = threadIdx.x;
  if (b < 128) {
    // T2t[n][s] = sum_{o<1024} T1[s,o] * fuse_w[n,o]
    const int n = b * 16 + (tid >> 4);
    const int s = tid & 15;
    const float* fr = fuse_w + (size_t)n * 2048;
    const float* tr = T1 + s * 1024;
    float acc = 0.f;
    for (int o = 0; o < 1024; o += 4) {
      float4 f = *(const float4*)(fr + o);
      float4 t = *(const float4*)(tr + o);
      acc += f.x * t.x + f.y * t.y + f.z * t.z + f.w * t.w;
    }
    T2t[n * 16 + s] = acc;
  } else {
    // bias_z[n] = fuse_b[n] + sum_o ha_b[o]*F_a[n,o] + sum_o b_H[o]*F_b[n,o]
    const int n = (b - 128) * 256 + tid;
    float acc = fuse_b[n];
    const float* fr = fuse_w + (size_t)n * 2048;
    for (int o = 0; o < 1024; o += 4) {
      float4 fa = *(const float4*)(fr + o);
      float4 fb = *(const float4*)(fr + 1024 + o);
      float4 ha = *(const float4*)(ha_b + o);
      float4 bh = *(const float4*)(b_H + o);
      acc += fa.x * ha.x + fa.y * ha.y + fa.z * ha.z + fa.w * ha.w;
      acc += fb.x * bh.x + fb.y * bh.y + fb.z * bh.z + fb.w * bh.w;
    }
    bias_z[n] = acc;
  }
}

// ---------------------------------------------------------------------------
// z_a[m,n] = bias_z[n] + sum_s s16[m,s]*T2t[n,s]; s16 from split-K P partials.
// ---------------------------------------------------------------------------
__global__ __launch_bounds__(256) void za_kernel(
    const bf16* __restrict__ P0, const bf16* __restrict__ P1,
    const float* __restrict__ T2t,
    const float* __restrict__ cvec, const float* __restrict__ bias_z,
    bf16* __restrict__ z)
{
  __shared__ float s16t[32][16];
  const int tid = threadIdx.x;
  const int tok0 = blockIdx.x * 32;
  for (int p = tid; p < 512; p += 256) {
    const int t = p >> 4, s = p & 15;
    const int tok = tok0 + t;
    const int l = tok & (SEQ - 1), bb = tok >> 12;
    float acc = cvec[s];
#pragma unroll
    for (int k = 0; k < 4; ++k) {
      const int r = l - 1 + k;
      if ((unsigned)r < (unsigned)SEQ) {
        const size_t idx = ((size_t)bb * SEQ + r) * 128 + k * 16 + s;
        acc += (float)P0[idx] + (float)P1[idx];
      }
    }
    s16t[t][s] = acc;
  }
  const int c0 = tid * 8;
  float t2[8][16], bz[8];
#pragma unroll
  for (int j = 0; j < 8; ++j) {
    bz[j] = bias_z[c0 + j];
#pragma unroll
    for (int q = 0; q < 4; ++q) {
      float4 v = ((const float4*)(T2t + (size_t)(c0 + j) * 16))[q];
      t2[j][q * 4 + 0] = v.x; t2[j][q * 4 + 1] = v.y;
      t2[j][q * 4 + 2] = v.z; t2[j][q * 4 + 3] = v.w;
    }
  }
  __syncthreads();
  for (int t = 0; t < 32; ++t) {
    float sv[16];
#pragma unroll
    for (int s = 0; s < 16; ++s) sv[s] = s16t[t][s];
    bf16x8 o;
#pragma unroll
    for (int j = 0; j < 8; ++j) {
      float a = bz[j];
#pragma unroll
      for (int s = 0; s < 16; ++s) a += sv[s] * t2[j][s];
      o[j] = (bf16)a;
    }
    *(bf16x8*)(z + (size_t)(tok0 + t) * 2048 + c0) = o;
  }
}

// ---------------------------------------------------------------------------
extern "C" void kernel_launch(void* const* d_in, const int* in_sizes, int n_in,
                              void* d_out, int out_size, void* d_ws, size_t ws_size,
                              hipStream_t stream)
{
  const float* x      = (const float*)d_in[0];
  const float* norm_w = (const float*)d_in[1];
  const float* in_w   = (const float*)d_in[2];
  const float* in_b   = (const float*)d_in[3];
  const float* dwa_k  = (const float*)d_in[4];
  const float* dwa_b  = (const float*)d_in[5];
  const float* Amat   = (const float*)d_in[6];
  const float* Bm     = (const float*)d_in[7];
  const float* sym_k  = (const float*)d_in[8];
  const float* sym_b  = (const float*)d_in[9];
  const float* pw_w   = (const float*)d_in[10];
  const float* pw_b   = (const float*)d_in[11];
  const float* ha_w   = (const float*)d_in[12];
  const float* ha_b   = (const float*)d_in[13];
  const float* hb_w   = (const float*)d_in[14];
  const float* hb_b   = (const float*)d_in[15];
  const float* fuse_w = (const float*)d_in[16];
  const float* fuse_b = (const float*)d_in[17];
  const float* out_w  = (const float*)d_in[18];
  const float* out_b  = (const float*)d_in[19];
  float* out = (float*)d_out;

  char* ws = (char*)d_ws;
  const size_t MB = 1u << 20, KB = 1u << 10;
  // Overlay plan (peak ~220.8 MB; 221 proven to fit):
  //  R0 [0,64):   in_wbf[0,8) + hnorm[8,40)  ->  bsilu
  //  R1 [64,128): val  ->  z_a  ->  y2 (B-GEMM in-place)
  //  R2 [128,192): gate
  bf16*  in_wbf  = (bf16*)(ws + 0);
  bf16*  hnorm   = (bf16*)(ws + 8 * MB);
  bf16*  bsilu   = (bf16*)(ws + 0);
  bf16*  valp    = (bf16*)(ws + 64 * MB);
  bf16*  zbuf    = (bf16*)(ws + 64 * MB);   // z_a then y2 (in-place)
  bf16*  gatep   = (bf16*)(ws + 128 * MB);
  bf16*  Pbuf    = (bf16*)(ws + 192 * MB);              // 8 MB (2 split-K parts)
  bf16*  pwT_bf  = (bf16*)(ws + 200 * MB);              // 8 MB (dead after Ht)
  bf16*  WB_bf   = (bf16*)(ws + 200 * MB);              // 8 MB (overlays pwT)
  bf16*  hb_bf   = (bf16*)(ws + 208 * MB);              // 4 MB (dead after Ht)
  bf16*  Fb_bf   = (bf16*)(ws + 208 * MB);              // 4 MB (written post-Ht)
  bf16*  Ht_bf   = (bf16*)(ws + 212 * MB);              // 4 MB
  bf16*  out_bf  = (bf16*)(ws + 216 * MB);              // 4 MB
  float* T1      = (float*)(ws + 220 * MB);             // 64 KB
  float* cvec    = (float*)(ws + 220 * MB + 64 * KB);   // 64 B (pad to 4K)
  float* b_H     = (float*)(ws + 220 * MB + 68 * KB);   // 4 KB
  float* bias_z  = (float*)(ws + 220 * MB + 72 * KB);   // 8 KB
  bf16*  Wp      = (bf16*)(ws + 220 * MB + 80 * KB);    // 512 KB
  float* T2t     = (float*)(ws + 220 * MB + 592 * KB);  // 128 KB -> 220.70 MB

  // ---- weight prep (6 launches) ----
  prep_cvt_kernel<<<8192, 256, 0, stream>>>(in_w, hb_w, out_w, in_wbf, hb_bf, out_bf);
  transpose_kernel<<<dim3(64, 64), 256, 0, stream>>>(pw_w, pwT_bf);
  // Ht[d,o] = sum_c pw_w[c,d]*hb_w[o,c]  (= (hb_w@pw_w)^T)
  gemm_bt<EPI_PLAIN><<<dim3(8, 16), 256, 0, stream>>>(
      pwT_bf, hb_bf, nullptr, Ht_bf, nullptr, nullptr, nullptr, nullptr, 1024, 2048, 1024, 0);
  prep_small_kernel<<<3085, 256, 0, stream>>>(
      Bm, ha_w, dwa_b, dwa_k, Amat, hb_w, pw_b, hb_b, fuse_w,
      T1, cvec, b_H, Wp, Fb_bf);
  // W_B[n,d] = sum_o F_b[n,o]*Ht[d,o]  (= F_b@hb_w@pw_w)
  gemm_bt<EPI_PLAIN><<<dim3(16, 16), 256, 0, stream>>>(
      Fb_bf, Ht_bf, nullptr, WB_bf, nullptr, nullptr, nullptr, nullptr, 2048, 1024, 2048, 0);
  prep_fuse_kernel<<<136, 256, 0, stream>>>(T1, fuse_w, fuse_b, ha_b, b_H, T2t, bias_z);

  // ---- main chain ----
  rmsnorm_kernel<<<MTOK, 256, 0, stream>>>(x, norm_w, hnorm);
  // in-proj: gate = sigmoid(h[:, :DI]), val = h[:, DI:]
  gemm_bt<EPI_SPLIT><<<dim3(32, 128), 256, 0, stream>>>(
      hnorm, in_wbf, in_b, gatep, valp, nullptr, nullptr, nullptr, 4096, 1024, DI, 0);
  // 9-tap conv + silu (val -> bsilu, overlays dead in_wbf/hnorm)
  conv_kernel<<<dim3(SEQ / TL2, 2, BATCH), 256, 0, stream>>>(
      valp, sym_k, sym_b, bsilu);
  // skinny P GEMM, split-K=2: P = val @ Wp^T  (N=128 padded)
  gemm_bt<EPI_PLAIN, true><<<dim3(2, 128), 256, 0, stream>>>(
      valp, Wp, nullptr, Pbuf, nullptr, nullptr, nullptr, nullptr, 128, 2048, 128, 0);
  // z_a = s16 @ T2 + bias_z  (writes R1, val now dead)
  za_kernel<<<MTOK / 32, 256, 0, stream>>>(
      Pbuf, Pbuf + (size_t)MTOK * 128, T2t, cvec, bias_z, zbuf);
  // B-GEMM: y2 = gate * (bsilu @ W_B^T + z_a)   [in-place over zbuf]
  gemm_bt<EPI_GATEADD><<<dim3(16, 128), 256, 0, stream>>>(
      bsilu, WB_bf, nullptr, zbuf, nullptr, gatep, nullptr, nullptr, 2048, 2048, 2048, 0);
  // out GEMM + residual -> fp32 d_out
  gemm_bt<EPI_RES><<<dim3(8, 128), 256, 0, stream>>>(
      zbuf, out_bf, out_b, nullptr, nullptr, nullptr, out, x, 1024, 2048, 1024, 0);
}